// Round 14
// baseline (213.225 us; speedup 1.0000x reference)
//
#include <hip/hip_runtime.h>

// ---------------------------------------------------------------------------
// GNN: 3x GraphConv(H=64) + global_mean_pool + Linear(64->2)
// N=100000, E=1200000, G=256, C_IN=1, C_OUT=2
//
// Round-14: round-13 (best, 125.1us) plus:
//  - sort3a's 14-barrier LDS scan -> shfl_up wave scan (2 barriers)
//  - k_final merged into k_pool (last-block-done ticket; atomic reads of gacc
//    for cross-XCD coherence)
// 6 kernels total.
// ---------------------------------------------------------------------------

#define BKT_SHIFT 7
#define BKT_SZ    128
#define NBK_MAX   1024
#define CHUNK     4096   // edges per sort block (16 per thread)
#define CAP       2048   // fixed bucket capacity (avg 1536, 13 sigma slack)

static __device__ __forceinline__ float4 ld4(const float* p) {
    return *reinterpret_cast<const float4*>(p);
}
static __device__ __forceinline__ float rdlane(float v, int i) {
    return __int_as_float(__builtin_amdgcn_readlane(__float_as_int(v), i));
}

// Zero cursor/gacc/ticket (grid-stride) + precompute MC4, b3W.
__global__ void k_small(const float* __restrict__ W3_rel, const float* __restrict__ b3,
                        const float* __restrict__ W3_root, const float* __restrict__ W_lin,
                        float4* __restrict__ MC4, float* __restrict__ b3W,
                        int* __restrict__ zbase, int zwords)
{
    int gt = blockIdx.x * 256 + threadIdx.x;
    for (int i = gt; i < zwords; i += gridDim.x * 256) zbase[i] = 0;

    if (blockIdx.x == 0) {
        int t = threadIdx.x;
        if (t < 64) {
            float sr0 = 0.f, sr1 = 0.f, so0 = 0.f, so1 = 0.f;
            for (int k = 0; k < 64; ++k) {
                float wl0 = W_lin[k * 2 + 0], wl1 = W_lin[k * 2 + 1];
                sr0 += W3_rel[t * 64 + k] * wl0;
                sr1 += W3_rel[t * 64 + k] * wl1;
                so0 += W3_root[t * 64 + k] * wl0;
                so1 += W3_root[t * 64 + k] * wl1;
            }
            MC4[t] = make_float4(sr0, sr1, so0, so1);
        }
        if (t < 2) {
            float s = 0.f;
            for (int k = 0; k < 64; ++k) s += b3[k] * W_lin[k * 2 + t];
            b3W[t] = s;
        }
    }
}

// ---- level-1: block counting sort into fixed-capacity bucket regions -------
// ebuf[b*CAP + i] = { pack = dl<<17 | src , w }; cursor[b] = bucket count.
__global__ __launch_bounds__(256) void k_scatter2(const int* __restrict__ src,
                                                  const int* __restrict__ dst,
                                                  const float* __restrict__ ew,
                                                  int* __restrict__ cursor,
                                                  int2* __restrict__ ebuf, int E, int NBK)
{
    __shared__ int lofs[NBK_MAX + 1];
    __shared__ int rcur[NBK_MAX];
    __shared__ int delta[NBK_MAX];
    __shared__ int2 stage[CHUNK];
    __shared__ unsigned short sbkt[CHUNK];
    __shared__ int tmp[256];

    const int t = threadIdx.x;
    const int e0 = blockIdx.x * CHUNK;
    const int cnt = min(CHUNK, E - e0);

    for (int i = t; i < NBK; i += 256) lofs[i] = 0;
    __syncthreads();

    int   myb[16];
    int   mypk[16];
    float myw[16];
#pragma unroll
    for (int k = 0; k < 16; ++k) {
        int e = e0 + k * 256 + t;
        myb[k] = -1;
        if (e < E) {
            int d = dst[e];
            int b = d >> BKT_SHIFT;
            myb[k]  = b;
            mypk[k] = ((d & (BKT_SZ - 1)) << 17) | src[e];
            myw[k]  = ew[e];
            atomicAdd(&lofs[b], 1);
        }
    }
    __syncthreads();

    int loc[4]; int s = 0;
#pragma unroll
    for (int u = 0; u < 4; ++u) {
        int idx = t * 4 + u;
        loc[u] = (idx < NBK) ? lofs[idx] : 0;
        s += loc[u];
    }
    tmp[t] = s;
    __syncthreads();
    for (int off = 1; off < 256; off <<= 1) {
        int v = (t >= off) ? tmp[t - off] : 0;
        __syncthreads();
        tmp[t] += v;
        __syncthreads();
    }
    int run = tmp[t] - s;
#pragma unroll
    for (int u = 0; u < 4; ++u) {
        int idx = t * 4 + u;
        if (idx < NBK) { lofs[idx] = run; rcur[idx] = run; }
        run += loc[u];
    }
    if (t == 255) lofs[NBK] = run;
    __syncthreads();

    // reserve per-bucket runs directly in the bucket's fixed region
    for (int b = t; b < NBK; b += 256) {
        int c = lofs[b + 1] - lofs[b];
        if (c > 0) {
            int g0 = atomicAdd(&cursor[b], c);
            delta[b] = b * CAP + g0 - lofs[b];
        }
    }
    __syncthreads();

#pragma unroll
    for (int k = 0; k < 16; ++k) {
        if (myb[k] >= 0) {
            int p = atomicAdd(&rcur[myb[k]], 1);
            stage[p] = make_int2(mypk[k], __float_as_int(myw[k]));
            sbkt[p]  = (unsigned short)myb[k];
        }
    }
    __syncthreads();

    for (int i = t; i < cnt; i += 256) {
        int b = sbkt[i];
        ebuf[delta[b] + i] = stage[i];
    }
}

// ---- level-2: per-bucket dl sort -> CSR + rowptr2, fused with agg1 ---------
__global__ __launch_bounds__(256) void k_sort3a(const int2* __restrict__ ebuf,
                                                const int* __restrict__ bcnt,
                                                const float* __restrict__ x,
                                                int2* __restrict__ rowptr2,
                                                int2* __restrict__ csr,
                                                float2* __restrict__ axn, int N)
{
    __shared__ int cnt_[BKT_SZ];
    __shared__ int base_[BKT_SZ];
    __shared__ int cur_[BKT_SZ];
    __shared__ float a1[BKT_SZ];
    __shared__ int wsum;

    const int t = threadIdx.x;
    const int bk = blockIdx.x;
    if (t < BKT_SZ) { cnt_[t] = 0; a1[t] = 0.f; }
    __syncthreads();

    const int beg = bk * CAP;
    const int end = beg + bcnt[bk];
    for (int i = beg + t; i < end; i += 256) {
        int dl = ebuf[i].x >> 17;
        atomicAdd(&cnt_[dl], 1);
    }
    __syncthreads();

    // exclusive scan of cnt_[0..127] via shfl_up (wave 0: 0-63, wave 1: 64-127)
    int val = 0, sinc = 0;
    if (t < BKT_SZ) {
        int lane = t & 63;
        val = cnt_[t];
        sinc = val;
#pragma unroll
        for (int off = 1; off < 64; off <<= 1) {
            int u = __shfl_up(sinc, off);
            if (lane >= off) sinc += u;
        }
        if (t == 63) wsum = sinc;
    }
    __syncthreads();
    if (t < BKT_SZ) {
        int excl = sinc - val + ((t >= 64) ? wsum : 0);
        base_[t] = excl;
        cur_[t] = 0;
        int n = bk * BKT_SZ + t;
        if (n < N) rowptr2[n] = make_int2(beg + excl, beg + excl + val);
    }
    __syncthreads();

    for (int i = beg + t; i < end; i += 256) {
        int2 pw = ebuf[i];
        int dl = pw.x >> 17;
        int s_ = pw.x & 0x1FFFF;
        int pos = beg + base_[dl] + atomicAdd(&cur_[dl], 1);
        csr[pos] = make_int2(pw.x, pw.y);
        atomicAdd(&a1[dl], __int_as_float(pw.y) * x[s_]);   // agg1 fused
    }
    __syncthreads();

    int n = bk * BKT_SZ + t;
    if (t < BKT_SZ && n < N) axn[n] = make_float2(a1[t], x[n]);
}

// ---- layer 2 aggregation: wave per node, lane = channel, padded x8 loop ----
__global__ __launch_bounds__(256) void k_agg2(const int2* __restrict__ csr,
                                              const int2* __restrict__ rowptr2,
                                              const float2* __restrict__ axn,
                                              const float* __restrict__ W1_rel,
                                              const float* __restrict__ b1,
                                              const float* __restrict__ W1_root,
                                              float* __restrict__ agg2, int N)
{
    int n = (blockIdx.x * 256 + threadIdx.x) >> 6;
    int lane = threadIdx.x & 63;
    if (n >= N) return;
    float wrel = W1_rel[lane], wroot = W1_root[lane], bj = b1[lane];
    int2 rp = rowptr2[n];
    float acc = 0.f;

    for (int base = rp.x; base < rp.y; base += 64) {
        int e = base + lane;
        float wv = 0.f;                       // w=0 for dead lanes kills their term
        float2 ax = make_float2(0.f, 0.f);
        if (e < rp.y) {
            int2 sw = csr[e];                 // coalesced 8B/lane
            wv = __int_as_float(sw.y);
            ax = axn[sw.x & 0x1FFFF];         // per-lane gather
        }
        int m8 = (min(rp.y - base, 64) + 7) & ~7;
        for (int i = 0; i < m8; i += 8) {
#pragma unroll
            for (int u = 0; u < 8; ++u) {
                float wi = rdlane(wv, i + u);
                float ai = rdlane(ax.x, i + u);
                float xi = rdlane(ax.y, i + u);
                float h = fmaxf(fmaf(ai, wrel, fmaf(xi, wroot, bj)), 0.f);
                acc = fmaf(wi, h, acc);
            }
        }
    }
    agg2[(size_t)n * 64 + lane] = acc;
}

// ---- layer-2 node GEMM + layer-3 fold (round-9, unchanged) -----------------
__global__ __launch_bounds__(256) void k_node2(const float* __restrict__ agg2,
                                               const float2* __restrict__ axn,
                                               const float* __restrict__ W2_rel,
                                               const float* __restrict__ W2_root,
                                               const float* __restrict__ b2,
                                               const float* __restrict__ W1_rel,
                                               const float* __restrict__ b1,
                                               const float* __restrict__ W1_root,
                                               const float* __restrict__ MCf,   // [64][4]
                                               float2* __restrict__ z01,
                                               float2* __restrict__ z23, int N)
{
    __shared__ float As[128 * 65];

    const int t = threadIdx.x;
    const int n0 = blockIdx.x * 128;

#pragma unroll
    for (int it = 0; it < 8; ++it) {
        int idx = it * 256 + t;
        int nl = idx >> 4, q4 = (idx & 15) << 2;
        int n = n0 + nl;
        float4 a = (n < N) ? ld4(&agg2[(size_t)n * 64 + q4])
                           : make_float4(0.f, 0.f, 0.f, 0.f);
        float* row = &As[nl * 65 + q4];
        row[0] = a.x; row[1] = a.y; row[2] = a.z; row[3] = a.w;
    }
    __syncthreads();

    const int lane = t & 63;
    const int g = (t >> 7) & 1;
    const int hs = __builtin_amdgcn_readfirstlane((t >> 6) & 1);
    const int nl = g * 64 + lane;
    const int n = n0 + nl;
    float2 ax = (n < N) ? axn[n] : make_float2(0.f, 0.f);

    float4 acc[8];
#pragma unroll
    for (int q = 0; q < 8; ++q) acc[q] = make_float4(0.f, 0.f, 0.f, 0.f);

    const float* Asr = &As[nl * 65];

    for (int c = 0; c < 8; ++c) {
        float a_[8];
#pragma unroll
        for (int i = 0; i < 8; ++i) a_[i] = Asr[c * 8 + i];
#pragma unroll
        for (int i = 0; i < 8; ++i) {
            const float* wr = &W2_rel[(size_t)(c * 8 + i) * 64 + hs * 32];
#pragma unroll
            for (int q = 0; q < 8; ++q) {
                float4 w = ld4(wr + q * 4);
                acc[q].x = fmaf(a_[i], w.x, acc[q].x);
                acc[q].y = fmaf(a_[i], w.y, acc[q].y);
                acc[q].z = fmaf(a_[i], w.z, acc[q].z);
                acc[q].w = fmaf(a_[i], w.w, acc[q].w);
            }
        }
    }

    for (int c = 0; c < 8; ++c) {
        int k0 = c * 8;
        float4 w1ra = ld4(&W1_rel[k0]),  w1rb = ld4(&W1_rel[k0 + 4]);
        float4 w1oa = ld4(&W1_root[k0]), w1ob = ld4(&W1_root[k0 + 4]);
        float4 b1a  = ld4(&b1[k0]),      b1b  = ld4(&b1[k0 + 4]);
        float hk[8];
        hk[0] = fmaxf(fmaf(ax.x, w1ra.x, fmaf(ax.y, w1oa.x, b1a.x)), 0.f);
        hk[1] = fmaxf(fmaf(ax.x, w1ra.y, fmaf(ax.y, w1oa.y, b1a.y)), 0.f);
        hk[2] = fmaxf(fmaf(ax.x, w1ra.z, fmaf(ax.y, w1oa.z, b1a.z)), 0.f);
        hk[3] = fmaxf(fmaf(ax.x, w1ra.w, fmaf(ax.y, w1oa.w, b1a.w)), 0.f);
        hk[4] = fmaxf(fmaf(ax.x, w1rb.x, fmaf(ax.y, w1ob.x, b1b.x)), 0.f);
        hk[5] = fmaxf(fmaf(ax.x, w1rb.y, fmaf(ax.y, w1ob.y, b1b.y)), 0.f);
        hk[6] = fmaxf(fmaf(ax.x, w1rb.z, fmaf(ax.y, w1ob.z, b1b.z)), 0.f);
        hk[7] = fmaxf(fmaf(ax.x, w1rb.w, fmaf(ax.y, w1ob.w, b1b.w)), 0.f);
#pragma unroll
        for (int i = 0; i < 8; ++i) {
            const float* wo = &W2_root[(size_t)(k0 + i) * 64 + hs * 32];
#pragma unroll
            for (int q = 0; q < 8; ++q) {
                float4 w = ld4(wo + q * 4);
                acc[q].x = fmaf(hk[i], w.x, acc[q].x);
                acc[q].y = fmaf(hk[i], w.y, acc[q].y);
                acc[q].z = fmaf(hk[i], w.z, acc[q].z);
                acc[q].w = fmaf(hk[i], w.w, acc[q].w);
            }
        }
    }

    float z0 = 0.f, z1 = 0.f, z2 = 0.f, z3 = 0.f;
    const float* b2h = &b2[hs * 32];
#pragma unroll
    for (int q = 0; q < 8; ++q) {
        float4 bq = ld4(b2h + q * 4);
        int jb = hs * 32 + q * 4;
        float h2;
        h2 = fmaxf(acc[q].x + bq.x, 0.f);
        { const float* m = &MCf[(jb + 0) * 4];
          z0 = fmaf(h2, m[0], z0); z1 = fmaf(h2, m[1], z1);
          z2 = fmaf(h2, m[2], z2); z3 = fmaf(h2, m[3], z3); }
        h2 = fmaxf(acc[q].y + bq.y, 0.f);
        { const float* m = &MCf[(jb + 1) * 4];
          z0 = fmaf(h2, m[0], z0); z1 = fmaf(h2, m[1], z1);
          z2 = fmaf(h2, m[2], z2); z3 = fmaf(h2, m[3], z3); }
        h2 = fmaxf(acc[q].z + bq.z, 0.f);
        { const float* m = &MCf[(jb + 2) * 4];
          z0 = fmaf(h2, m[0], z0); z1 = fmaf(h2, m[1], z1);
          z2 = fmaf(h2, m[2], z2); z3 = fmaf(h2, m[3], z3); }
        h2 = fmaxf(acc[q].w + bq.w, 0.f);
        { const float* m = &MCf[(jb + 3) * 4];
          z0 = fmaf(h2, m[0], z0); z1 = fmaf(h2, m[1], z1);
          z2 = fmaf(h2, m[2], z2); z3 = fmaf(h2, m[3], z3); }
    }

    __syncthreads();
    float* zs = As;
    *reinterpret_cast<float4*>(&zs[(nl * 2 + hs) * 4]) = make_float4(z0, z1, z2, z3);
    __syncthreads();
    if (hs == 0 && n < N) {
        float4 p0 = *reinterpret_cast<float4*>(&zs[(nl * 2 + 0) * 4]);
        float4 p1 = *reinterpret_cast<float4*>(&zs[(nl * 2 + 1) * 4]);
        z01[n] = make_float2(p0.x + p1.x, p0.y + p1.y);
        z23[n] = make_float2(p0.z + p1.z, p0.w + p1.w);
    }
}

// ---- pool + final fused: last-block-done finishes the output ---------------
__global__ __launch_bounds__(256) void k_poolf(const int2* __restrict__ csr,
                                               const int2* __restrict__ rowptr2,
                                               const int* __restrict__ batch,
                                               const float2* __restrict__ z01,
                                               const float2* __restrict__ z23,
                                               float* __restrict__ gacc,
                                               int* __restrict__ ticket,
                                               const float* __restrict__ b3W,
                                               const float* __restrict__ b_lin,
                                               float* __restrict__ out,
                                               int N, int G, int nblocks)
{
    __shared__ float lds[5 * 256];
    __shared__ int amLast;
    for (int i = threadIdx.x; i < 5 * G; i += 256) lds[i] = 0.f;
    __syncthreads();

    int gt = blockIdx.x * 256 + threadIdx.x;
    int n = gt >> 2, p = gt & 3;
    if (n < N) {
        int2 rp = rowptr2[n];
        float s0 = 0.f, s1 = 0.f;
        for (int e = rp.x + p; e < rp.y; e += 4) {
            int2 sw = csr[e];
            float w = __int_as_float(sw.y);
            float2 zz = z01[sw.x & 0x1FFFF];
            s0 = fmaf(w, zz.x, s0);
            s1 = fmaf(w, zz.y, s1);
        }
        s0 += __shfl_xor(s0, 1);
        s0 += __shfl_xor(s0, 2);
        s1 += __shfl_xor(s1, 1);
        s1 += __shfl_xor(s1, 2);
        if (p == 0) {
            int bg = batch[n];
            float2 zw = z23[n];
            atomicAdd(&lds[bg * 5 + 0], s0);
            atomicAdd(&lds[bg * 5 + 1], s1);
            atomicAdd(&lds[bg * 5 + 2], zw.x);
            atomicAdd(&lds[bg * 5 + 3], zw.y);
            atomicAdd(&lds[bg * 5 + 4], 1.0f);
        }
    }
    __syncthreads();
    for (int i = threadIdx.x; i < 5 * G; i += 256) {
        float v = lds[i];
        if (v != 0.f) atomicAdd(&gacc[i], v);
    }
    __threadfence();
    __syncthreads();
    if (threadIdx.x == 0) {
        int tkt = atomicAdd(ticket, 1);
        amLast = (tkt == nblocks - 1);
    }
    __syncthreads();
    if (amLast) {
        __threadfence();
        for (int i = threadIdx.x; i < 2 * G; i += 256) {
            int g = i >> 1, c = i & 1;
            float cnt = atomicAdd(&gacc[g * 5 + 4], 0.f);      // coherent reads
            float ed  = atomicAdd(&gacc[g * 5 + c], 0.f);
            float nd  = atomicAdd(&gacc[g * 5 + 2 + c], 0.f);
            float s = ed + nd + cnt * b3W[c];
            out[i] = s / fmaxf(cnt, 1.f) + b_lin[c];
        }
    }
}

extern "C" void kernel_launch(void* const* d_in, const int* in_sizes, int n_in,
                              void* d_out, int out_size, void* d_ws, size_t ws_size,
                              hipStream_t stream)
{
    const float* x       = (const float*)d_in[0];
    const int*   ei      = (const int*)  d_in[1];
    const int*   batch   = (const int*)  d_in[2];
    const float* ew      = (const float*)d_in[3];
    const float* W1_rel  = (const float*)d_in[4];
    const float* b1      = (const float*)d_in[5];
    const float* W1_root = (const float*)d_in[6];
    const float* W2_rel  = (const float*)d_in[7];
    const float* b2      = (const float*)d_in[8];
    const float* W2_root = (const float*)d_in[9];
    const float* W3_rel  = (const float*)d_in[10];
    const float* b3      = (const float*)d_in[11];
    const float* W3_root = (const float*)d_in[12];
    const float* W_lin   = (const float*)d_in[13];
    const float* b_lin   = (const float*)d_in[14];
    float* out = (float*)d_out;

    const int N = in_sizes[0];
    const int E = in_sizes[3];
    const int G = out_size / 2;
    const int NBK = (N + BKT_SZ - 1) >> BKT_SHIFT;   // 782
    const int EB  = (E + CHUNK - 1) / CHUNK;         // 293
    const int* src = ei;
    const int* dst = ei + E;

    char* wsb = (char*)d_ws;
    size_t o = 0;
    auto take = [&](size_t bytes) -> char* {
        char* p = wsb + o;
        o += (bytes + 15) & ~(size_t)15;
        return p;
    };
    int*    cursor  = (int*)   take((size_t)NBK * 4);
    float*  gacc    = (float*) take((size_t)G * 5 * 4);
    int*    ticket  = (int*)   take(16);
    size_t  zero_bytes = o;                          // cursor+gacc+ticket
    int2*   rowptr2 = (int2*)  take((size_t)N * 8);
    int2*   ebuf    = (int2*)  take((size_t)NBK * CAP * 8);
    int2*   csr     = (int2*)  take((size_t)NBK * CAP * 8);
    float2* axn     = (float2*)take((size_t)N * 8);
    float*  agg2    = (float*) take((size_t)N * 64 * 4);
    float2* z01     = (float2*)take((size_t)N * 8);
    float2* z23     = (float2*)take((size_t)N * 8);
    float4* MC4     = (float4*)take(64 * 16);
    float*  b3W     = (float*) take(4 * 4);

    const int zwords = (int)(zero_bytes / 4);

    hipLaunchKernelGGL(k_small, dim3(8), dim3(256), 0, stream,
                       W3_rel, b3, W3_root, W_lin, MC4, b3W,
                       (int*)d_ws, zwords);

    hipLaunchKernelGGL(k_scatter2, dim3(EB), dim3(256), 0, stream,
                       src, dst, ew, cursor, ebuf, E, NBK);

    hipLaunchKernelGGL(k_sort3a, dim3(NBK), dim3(256), 0, stream,
                       ebuf, cursor, x, rowptr2, csr, axn, N);

    hipLaunchKernelGGL(k_agg2, dim3((N * 64 + 255) / 256), dim3(256), 0, stream,
                       csr, rowptr2, axn, W1_rel, b1, W1_root, agg2, N);

    hipLaunchKernelGGL(k_node2, dim3((N + 127) / 128), dim3(256), 0, stream,
                       agg2, axn, W2_rel, W2_root, b2, W1_rel, b1, W1_root,
                       (const float*)MC4, z01, z23, N);

    const int PB = (int)(((size_t)N * 4 + 255) / 256);
    hipLaunchKernelGGL(k_poolf, dim3(PB), dim3(256), 0, stream,
                       csr, rowptr2, batch, z01, z23, gacc, ticket,
                       b3W, b_lin, out, N, G, PB);
}

// Round 15
// 124.646 us; speedup vs baseline: 1.7106x; 1.7106x over previous
//
#include <hip/hip_runtime.h>

// ---------------------------------------------------------------------------
// GNN: 3x GraphConv(H=64) + global_mean_pool + Linear(64->2)
// N=100000, E=1200000, G=256, C_IN=1, C_OUT=2
//
// Round-15: round-13 structure (best, 125.1us) + sort3a shfl_up scan from
// round 14. The threadfence-based pool/final fusion (round 14, -88us
// regression: per-block device fences serialize at TCC) is reverted.
// 7 kernels.
// ---------------------------------------------------------------------------

#define BKT_SHIFT 7
#define BKT_SZ    128
#define NBK_MAX   1024
#define CHUNK     4096   // edges per sort block (16 per thread)
#define CAP       2048   // fixed bucket capacity (avg 1536, 13 sigma slack)

static __device__ __forceinline__ float4 ld4(const float* p) {
    return *reinterpret_cast<const float4*>(p);
}
static __device__ __forceinline__ float rdlane(float v, int i) {
    return __int_as_float(__builtin_amdgcn_readlane(__float_as_int(v), i));
}

// Zero cursor/gacc (grid-stride) + precompute MC4, b3W.
__global__ void k_small(const float* __restrict__ W3_rel, const float* __restrict__ b3,
                        const float* __restrict__ W3_root, const float* __restrict__ W_lin,
                        float4* __restrict__ MC4, float* __restrict__ b3W,
                        int* __restrict__ zbase, int zwords)
{
    int gt = blockIdx.x * 256 + threadIdx.x;
    for (int i = gt; i < zwords; i += gridDim.x * 256) zbase[i] = 0;

    if (blockIdx.x == 0) {
        int t = threadIdx.x;
        if (t < 64) {
            float sr0 = 0.f, sr1 = 0.f, so0 = 0.f, so1 = 0.f;
            for (int k = 0; k < 64; ++k) {
                float wl0 = W_lin[k * 2 + 0], wl1 = W_lin[k * 2 + 1];
                sr0 += W3_rel[t * 64 + k] * wl0;
                sr1 += W3_rel[t * 64 + k] * wl1;
                so0 += W3_root[t * 64 + k] * wl0;
                so1 += W3_root[t * 64 + k] * wl1;
            }
            MC4[t] = make_float4(sr0, sr1, so0, so1);
        }
        if (t < 2) {
            float s = 0.f;
            for (int k = 0; k < 64; ++k) s += b3[k] * W_lin[k * 2 + t];
            b3W[t] = s;
        }
    }
}

// ---- level-1: block counting sort into fixed-capacity bucket regions -------
// ebuf[b*CAP + i] = { pack = dl<<17 | src , w }; cursor[b] = bucket count.
__global__ __launch_bounds__(256) void k_scatter2(const int* __restrict__ src,
                                                  const int* __restrict__ dst,
                                                  const float* __restrict__ ew,
                                                  int* __restrict__ cursor,
                                                  int2* __restrict__ ebuf, int E, int NBK)
{
    __shared__ int lofs[NBK_MAX + 1];
    __shared__ int rcur[NBK_MAX];
    __shared__ int delta[NBK_MAX];
    __shared__ int2 stage[CHUNK];
    __shared__ unsigned short sbkt[CHUNK];
    __shared__ int tmp[256];

    const int t = threadIdx.x;
    const int e0 = blockIdx.x * CHUNK;
    const int cnt = min(CHUNK, E - e0);

    for (int i = t; i < NBK; i += 256) lofs[i] = 0;
    __syncthreads();

    int   myb[16];
    int   mypk[16];
    float myw[16];
#pragma unroll
    for (int k = 0; k < 16; ++k) {
        int e = e0 + k * 256 + t;
        myb[k] = -1;
        if (e < E) {
            int d = dst[e];
            int b = d >> BKT_SHIFT;
            myb[k]  = b;
            mypk[k] = ((d & (BKT_SZ - 1)) << 17) | src[e];
            myw[k]  = ew[e];
            atomicAdd(&lofs[b], 1);
        }
    }
    __syncthreads();

    int loc[4]; int s = 0;
#pragma unroll
    for (int u = 0; u < 4; ++u) {
        int idx = t * 4 + u;
        loc[u] = (idx < NBK) ? lofs[idx] : 0;
        s += loc[u];
    }
    tmp[t] = s;
    __syncthreads();
    for (int off = 1; off < 256; off <<= 1) {
        int v = (t >= off) ? tmp[t - off] : 0;
        __syncthreads();
        tmp[t] += v;
        __syncthreads();
    }
    int run = tmp[t] - s;
#pragma unroll
    for (int u = 0; u < 4; ++u) {
        int idx = t * 4 + u;
        if (idx < NBK) { lofs[idx] = run; rcur[idx] = run; }
        run += loc[u];
    }
    if (t == 255) lofs[NBK] = run;
    __syncthreads();

    // reserve per-bucket runs directly in the bucket's fixed region
    for (int b = t; b < NBK; b += 256) {
        int c = lofs[b + 1] - lofs[b];
        if (c > 0) {
            int g0 = atomicAdd(&cursor[b], c);
            delta[b] = b * CAP + g0 - lofs[b];
        }
    }
    __syncthreads();

#pragma unroll
    for (int k = 0; k < 16; ++k) {
        if (myb[k] >= 0) {
            int p = atomicAdd(&rcur[myb[k]], 1);
            stage[p] = make_int2(mypk[k], __float_as_int(myw[k]));
            sbkt[p]  = (unsigned short)myb[k];
        }
    }
    __syncthreads();

    for (int i = t; i < cnt; i += 256) {
        int b = sbkt[i];
        ebuf[delta[b] + i] = stage[i];
    }
}

// ---- level-2: per-bucket dl sort -> CSR + rowptr2, fused with agg1 ---------
__global__ __launch_bounds__(256) void k_sort3a(const int2* __restrict__ ebuf,
                                                const int* __restrict__ bcnt,
                                                const float* __restrict__ x,
                                                int2* __restrict__ rowptr2,
                                                int2* __restrict__ csr,
                                                float2* __restrict__ axn, int N)
{
    __shared__ int cnt_[BKT_SZ];
    __shared__ int base_[BKT_SZ];
    __shared__ int cur_[BKT_SZ];
    __shared__ float a1[BKT_SZ];
    __shared__ int wsum;

    const int t = threadIdx.x;
    const int bk = blockIdx.x;
    if (t < BKT_SZ) { cnt_[t] = 0; a1[t] = 0.f; }
    __syncthreads();

    const int beg = bk * CAP;
    const int end = beg + bcnt[bk];
    for (int i = beg + t; i < end; i += 256) {
        int dl = ebuf[i].x >> 17;
        atomicAdd(&cnt_[dl], 1);
    }
    __syncthreads();

    // exclusive scan of cnt_[0..127] via shfl_up (wave 0: 0-63, wave 1: 64-127)
    int val = 0, sinc = 0;
    if (t < BKT_SZ) {
        int lane = t & 63;
        val = cnt_[t];
        sinc = val;
#pragma unroll
        for (int off = 1; off < 64; off <<= 1) {
            int u = __shfl_up(sinc, off);
            if (lane >= off) sinc += u;
        }
        if (t == 63) wsum = sinc;
    }
    __syncthreads();
    if (t < BKT_SZ) {
        int excl = sinc - val + ((t >= 64) ? wsum : 0);
        base_[t] = excl;
        cur_[t] = 0;
        int n = bk * BKT_SZ + t;
        if (n < N) rowptr2[n] = make_int2(beg + excl, beg + excl + val);
    }
    __syncthreads();

    for (int i = beg + t; i < end; i += 256) {
        int2 pw = ebuf[i];
        int dl = pw.x >> 17;
        int s_ = pw.x & 0x1FFFF;
        int pos = beg + base_[dl] + atomicAdd(&cur_[dl], 1);
        csr[pos] = make_int2(pw.x, pw.y);
        atomicAdd(&a1[dl], __int_as_float(pw.y) * x[s_]);   // agg1 fused
    }
    __syncthreads();

    int n = bk * BKT_SZ + t;
    if (t < BKT_SZ && n < N) axn[n] = make_float2(a1[t], x[n]);
}

// ---- layer 2 aggregation: wave per node, lane = channel, padded x8 loop ----
__global__ __launch_bounds__(256) void k_agg2(const int2* __restrict__ csr,
                                              const int2* __restrict__ rowptr2,
                                              const float2* __restrict__ axn,
                                              const float* __restrict__ W1_rel,
                                              const float* __restrict__ b1,
                                              const float* __restrict__ W1_root,
                                              float* __restrict__ agg2, int N)
{
    int n = (blockIdx.x * 256 + threadIdx.x) >> 6;
    int lane = threadIdx.x & 63;
    if (n >= N) return;
    float wrel = W1_rel[lane], wroot = W1_root[lane], bj = b1[lane];
    int2 rp = rowptr2[n];
    float acc = 0.f;

    for (int base = rp.x; base < rp.y; base += 64) {
        int e = base + lane;
        float wv = 0.f;                       // w=0 for dead lanes kills their term
        float2 ax = make_float2(0.f, 0.f);
        if (e < rp.y) {
            int2 sw = csr[e];                 // coalesced 8B/lane
            wv = __int_as_float(sw.y);
            ax = axn[sw.x & 0x1FFFF];         // per-lane gather
        }
        int m8 = (min(rp.y - base, 64) + 7) & ~7;
        for (int i = 0; i < m8; i += 8) {
#pragma unroll
            for (int u = 0; u < 8; ++u) {
                float wi = rdlane(wv, i + u);
                float ai = rdlane(ax.x, i + u);
                float xi = rdlane(ax.y, i + u);
                float h = fmaxf(fmaf(ai, wrel, fmaf(xi, wroot, bj)), 0.f);
                acc = fmaf(wi, h, acc);
            }
        }
    }
    agg2[(size_t)n * 64 + lane] = acc;
}

// ---- layer-2 node GEMM + layer-3 fold (round-9, unchanged) -----------------
__global__ __launch_bounds__(256) void k_node2(const float* __restrict__ agg2,
                                               const float2* __restrict__ axn,
                                               const float* __restrict__ W2_rel,
                                               const float* __restrict__ W2_root,
                                               const float* __restrict__ b2,
                                               const float* __restrict__ W1_rel,
                                               const float* __restrict__ b1,
                                               const float* __restrict__ W1_root,
                                               const float* __restrict__ MCf,   // [64][4]
                                               float2* __restrict__ z01,
                                               float2* __restrict__ z23, int N)
{
    __shared__ float As[128 * 65];

    const int t = threadIdx.x;
    const int n0 = blockIdx.x * 128;

#pragma unroll
    for (int it = 0; it < 8; ++it) {
        int idx = it * 256 + t;
        int nl = idx >> 4, q4 = (idx & 15) << 2;
        int n = n0 + nl;
        float4 a = (n < N) ? ld4(&agg2[(size_t)n * 64 + q4])
                           : make_float4(0.f, 0.f, 0.f, 0.f);
        float* row = &As[nl * 65 + q4];
        row[0] = a.x; row[1] = a.y; row[2] = a.z; row[3] = a.w;
    }
    __syncthreads();

    const int lane = t & 63;
    const int g = (t >> 7) & 1;
    const int hs = __builtin_amdgcn_readfirstlane((t >> 6) & 1);
    const int nl = g * 64 + lane;
    const int n = n0 + nl;
    float2 ax = (n < N) ? axn[n] : make_float2(0.f, 0.f);

    float4 acc[8];
#pragma unroll
    for (int q = 0; q < 8; ++q) acc[q] = make_float4(0.f, 0.f, 0.f, 0.f);

    const float* Asr = &As[nl * 65];

    for (int c = 0; c < 8; ++c) {
        float a_[8];
#pragma unroll
        for (int i = 0; i < 8; ++i) a_[i] = Asr[c * 8 + i];
#pragma unroll
        for (int i = 0; i < 8; ++i) {
            const float* wr = &W2_rel[(size_t)(c * 8 + i) * 64 + hs * 32];
#pragma unroll
            for (int q = 0; q < 8; ++q) {
                float4 w = ld4(wr + q * 4);
                acc[q].x = fmaf(a_[i], w.x, acc[q].x);
                acc[q].y = fmaf(a_[i], w.y, acc[q].y);
                acc[q].z = fmaf(a_[i], w.z, acc[q].z);
                acc[q].w = fmaf(a_[i], w.w, acc[q].w);
            }
        }
    }

    for (int c = 0; c < 8; ++c) {
        int k0 = c * 8;
        float4 w1ra = ld4(&W1_rel[k0]),  w1rb = ld4(&W1_rel[k0 + 4]);
        float4 w1oa = ld4(&W1_root[k0]), w1ob = ld4(&W1_root[k0 + 4]);
        float4 b1a  = ld4(&b1[k0]),      b1b  = ld4(&b1[k0 + 4]);
        float hk[8];
        hk[0] = fmaxf(fmaf(ax.x, w1ra.x, fmaf(ax.y, w1oa.x, b1a.x)), 0.f);
        hk[1] = fmaxf(fmaf(ax.x, w1ra.y, fmaf(ax.y, w1oa.y, b1a.y)), 0.f);
        hk[2] = fmaxf(fmaf(ax.x, w1ra.z, fmaf(ax.y, w1oa.z, b1a.z)), 0.f);
        hk[3] = fmaxf(fmaf(ax.x, w1ra.w, fmaf(ax.y, w1oa.w, b1a.w)), 0.f);
        hk[4] = fmaxf(fmaf(ax.x, w1rb.x, fmaf(ax.y, w1ob.x, b1b.x)), 0.f);
        hk[5] = fmaxf(fmaf(ax.x, w1rb.y, fmaf(ax.y, w1ob.y, b1b.y)), 0.f);
        hk[6] = fmaxf(fmaf(ax.x, w1rb.z, fmaf(ax.y, w1ob.z, b1b.z)), 0.f);
        hk[7] = fmaxf(fmaf(ax.x, w1rb.w, fmaf(ax.y, w1ob.w, b1b.w)), 0.f);
#pragma unroll
        for (int i = 0; i < 8; ++i) {
            const float* wo = &W2_root[(size_t)(k0 + i) * 64 + hs * 32];
#pragma unroll
            for (int q = 0; q < 8; ++q) {
                float4 w = ld4(wo + q * 4);
                acc[q].x = fmaf(hk[i], w.x, acc[q].x);
                acc[q].y = fmaf(hk[i], w.y, acc[q].y);
                acc[q].z = fmaf(hk[i], w.z, acc[q].z);
                acc[q].w = fmaf(hk[i], w.w, acc[q].w);
            }
        }
    }

    float z0 = 0.f, z1 = 0.f, z2 = 0.f, z3 = 0.f;
    const float* b2h = &b2[hs * 32];
#pragma unroll
    for (int q = 0; q < 8; ++q) {
        float4 bq = ld4(b2h + q * 4);
        int jb = hs * 32 + q * 4;
        float h2;
        h2 = fmaxf(acc[q].x + bq.x, 0.f);
        { const float* m = &MCf[(jb + 0) * 4];
          z0 = fmaf(h2, m[0], z0); z1 = fmaf(h2, m[1], z1);
          z2 = fmaf(h2, m[2], z2); z3 = fmaf(h2, m[3], z3); }
        h2 = fmaxf(acc[q].y + bq.y, 0.f);
        { const float* m = &MCf[(jb + 1) * 4];
          z0 = fmaf(h2, m[0], z0); z1 = fmaf(h2, m[1], z1);
          z2 = fmaf(h2, m[2], z2); z3 = fmaf(h2, m[3], z3); }
        h2 = fmaxf(acc[q].z + bq.z, 0.f);
        { const float* m = &MCf[(jb + 2) * 4];
          z0 = fmaf(h2, m[0], z0); z1 = fmaf(h2, m[1], z1);
          z2 = fmaf(h2, m[2], z2); z3 = fmaf(h2, m[3], z3); }
        h2 = fmaxf(acc[q].w + bq.w, 0.f);
        { const float* m = &MCf[(jb + 3) * 4];
          z0 = fmaf(h2, m[0], z0); z1 = fmaf(h2, m[1], z1);
          z2 = fmaf(h2, m[2], z2); z3 = fmaf(h2, m[3], z3); }
    }

    __syncthreads();
    float* zs = As;
    *reinterpret_cast<float4*>(&zs[(nl * 2 + hs) * 4]) = make_float4(z0, z1, z2, z3);
    __syncthreads();
    if (hs == 0 && n < N) {
        float4 p0 = *reinterpret_cast<float4*>(&zs[(nl * 2 + 0) * 4]);
        float4 p1 = *reinterpret_cast<float4*>(&zs[(nl * 2 + 1) * 4]);
        z01[n] = make_float2(p0.x + p1.x, p0.y + p1.y);
        z23[n] = make_float2(p0.z + p1.z, p0.w + p1.w);
    }
}

// ---- pool: 4 threads per node, strided edges, shfl_xor combine -------------
__global__ __launch_bounds__(256) void k_pool(const int2* __restrict__ csr,
                                              const int2* __restrict__ rowptr2,
                                              const int* __restrict__ batch,
                                              const float2* __restrict__ z01,
                                              const float2* __restrict__ z23,
                                              float* __restrict__ gacc, int N, int G)
{
    __shared__ float lds[5 * 256];
    for (int i = threadIdx.x; i < 5 * G; i += 256) lds[i] = 0.f;
    __syncthreads();

    int gt = blockIdx.x * 256 + threadIdx.x;
    int n = gt >> 2, p = gt & 3;
    if (n < N) {
        int2 rp = rowptr2[n];
        float s0 = 0.f, s1 = 0.f;
        for (int e = rp.x + p; e < rp.y; e += 4) {
            int2 sw = csr[e];
            float w = __int_as_float(sw.y);
            float2 zz = z01[sw.x & 0x1FFFF];
            s0 = fmaf(w, zz.x, s0);
            s1 = fmaf(w, zz.y, s1);
        }
        s0 += __shfl_xor(s0, 1);
        s0 += __shfl_xor(s0, 2);
        s1 += __shfl_xor(s1, 1);
        s1 += __shfl_xor(s1, 2);
        if (p == 0) {
            int bg = batch[n];
            float2 zw = z23[n];
            atomicAdd(&lds[bg * 5 + 0], s0);
            atomicAdd(&lds[bg * 5 + 1], s1);
            atomicAdd(&lds[bg * 5 + 2], zw.x);
            atomicAdd(&lds[bg * 5 + 3], zw.y);
            atomicAdd(&lds[bg * 5 + 4], 1.0f);
        }
    }
    __syncthreads();
    for (int i = threadIdx.x; i < 5 * G; i += 256) {
        float v = lds[i];
        if (v != 0.f) atomicAdd(&gacc[i], v);
    }
}

__global__ void k_final(const float* __restrict__ gacc, const float* __restrict__ b3W,
                        const float* __restrict__ b_lin, float* __restrict__ out, int G)
{
    int t = blockIdx.x * blockDim.x + threadIdx.x;
    if (t < G * 2) {
        int g = t >> 1, c = t & 1;
        float cnt = gacc[g * 5 + 4];
        float s = gacc[g * 5 + c] + gacc[g * 5 + 2 + c] + cnt * b3W[c];
        out[t] = s / fmaxf(cnt, 1.f) + b_lin[c];
    }
}

extern "C" void kernel_launch(void* const* d_in, const int* in_sizes, int n_in,
                              void* d_out, int out_size, void* d_ws, size_t ws_size,
                              hipStream_t stream)
{
    const float* x       = (const float*)d_in[0];
    const int*   ei      = (const int*)  d_in[1];
    const int*   batch   = (const int*)  d_in[2];
    const float* ew      = (const float*)d_in[3];
    const float* W1_rel  = (const float*)d_in[4];
    const float* b1      = (const float*)d_in[5];
    const float* W1_root = (const float*)d_in[6];
    const float* W2_rel  = (const float*)d_in[7];
    const float* b2      = (const float*)d_in[8];
    const float* W2_root = (const float*)d_in[9];
    const float* W3_rel  = (const float*)d_in[10];
    const float* b3      = (const float*)d_in[11];
    const float* W3_root = (const float*)d_in[12];
    const float* W_lin   = (const float*)d_in[13];
    const float* b_lin   = (const float*)d_in[14];
    float* out = (float*)d_out;

    const int N = in_sizes[0];
    const int E = in_sizes[3];
    const int G = out_size / 2;
    const int NBK = (N + BKT_SZ - 1) >> BKT_SHIFT;   // 782
    const int EB  = (E + CHUNK - 1) / CHUNK;         // 293
    const int* src = ei;
    const int* dst = ei + E;

    char* wsb = (char*)d_ws;
    size_t o = 0;
    auto take = [&](size_t bytes) -> char* {
        char* p = wsb + o;
        o += (bytes + 15) & ~(size_t)15;
        return p;
    };
    int*    cursor  = (int*)   take((size_t)NBK * 4);
    float*  gacc    = (float*) take((size_t)G * 5 * 4);
    size_t  zero_bytes = o;                          // cursor+gacc
    int2*   rowptr2 = (int2*)  take((size_t)N * 8);
    int2*   ebuf    = (int2*)  take((size_t)NBK * CAP * 8);
    int2*   csr     = (int2*)  take((size_t)NBK * CAP * 8);
    float2* axn     = (float2*)take((size_t)N * 8);
    float*  agg2    = (float*) take((size_t)N * 64 * 4);
    float2* z01     = (float2*)take((size_t)N * 8);
    float2* z23     = (float2*)take((size_t)N * 8);
    float4* MC4     = (float4*)take(64 * 16);
    float*  b3W     = (float*) take(4 * 4);

    const int zwords = (int)(zero_bytes / 4);

    hipLaunchKernelGGL(k_small, dim3(8), dim3(256), 0, stream,
                       W3_rel, b3, W3_root, W_lin, MC4, b3W,
                       (int*)d_ws, zwords);

    hipLaunchKernelGGL(k_scatter2, dim3(EB), dim3(256), 0, stream,
                       src, dst, ew, cursor, ebuf, E, NBK);

    hipLaunchKernelGGL(k_sort3a, dim3(NBK), dim3(256), 0, stream,
                       ebuf, cursor, x, rowptr2, csr, axn, N);

    hipLaunchKernelGGL(k_agg2, dim3((N * 64 + 255) / 256), dim3(256), 0, stream,
                       csr, rowptr2, axn, W1_rel, b1, W1_root, agg2, N);

    hipLaunchKernelGGL(k_node2, dim3((N + 127) / 128), dim3(256), 0, stream,
                       agg2, axn, W2_rel, W2_root, b2, W1_rel, b1, W1_root,
                       (const float*)MC4, z01, z23, N);

    hipLaunchKernelGGL(k_pool, dim3(((size_t)N * 4 + 255) / 256), dim3(256), 0, stream,
                       csr, rowptr2, batch, z01, z23, gacc, N, G);

    hipLaunchKernelGGL(k_final, dim3((G * 2 + 255) / 256), dim3(256), 0, stream,
                       gacc, b3W, b_lin, out, G);
}